// Round 1
// baseline (5263.546 us; speedup 1.0000x reference)
//
#include <hip/hip_runtime.h>
#include <hip/hip_bf16.h>

typedef __attribute__((ext_vector_type(8))) short bfrag8;
typedef __attribute__((ext_vector_type(4))) float f32x4;

#define DEV static __device__ __forceinline__

constexpr int B_ = 512, T_ = 256, I_ = 256, H_ = 256;
constexpr int GROUPS = 8, BPG = 32, ROWS = 64, JPB = 8;
constexpr int NTHR = 512;
constexpr int LDK = 520;   // padded LDS row stride (bf16 elems) for K=512 tiles
constexpr int GLD = 33;    // gates LDS row stride (f32)

DEV unsigned short f2bf(float f) {
  __hip_bfloat16 h = __float2bfloat16(f);
  return *reinterpret_cast<unsigned short*>(&h);
}
DEV float bf2f(unsigned short u) {
  __hip_bfloat16 h;
  *reinterpret_cast<unsigned short*>(&h) = u;
  return __bfloat162float(h);
}
DEV float sigm(float x) { return 1.0f / (1.0f + __expf(-x)); }
DEV float tanh_f(float x) {
  float e = __expf(-2.0f * fabsf(x));
  float t = (1.0f - e) / (1.0f + e);
  return copysignf(t, x);
}

__global__ __launch_bounds__(NTHR, 2) void lstm_fused(
    const float* __restrict__ x, const int* __restrict__ is_init,
    const float* __restrict__ hx, const float* __restrict__ cx,
    const float* __restrict__ W_ih, const float* __restrict__ W_hh,
    const float* __restrict__ b_ih, const float* __restrict__ b_hh,
    const float* __restrict__ ln_w, const float* __restrict__ ln_b,
    float* __restrict__ out,
    unsigned short* __restrict__ hbuf, float* __restrict__ cts,
    int* __restrict__ cntg) {
  __shared__ unsigned short Wl[32 * LDK];   // [gate-slice 32][K 512+pad] bf16
  __shared__ unsigned short In[64 * LDK];   // [rows 64][x(256)|h(256)+pad] bf16
  __shared__ float gat[64 * GLD];           // gate pre-activations
  __shared__ float biasl[32];
  __shared__ float rml[64];

  const int tid = threadIdx.x;
  const int g = blockIdx.x & 7;      // group == XCD under round-robin dispatch
  const int mem = blockIdx.x >> 3;   // member 0..31 within group
  const int rowbase = g * ROWS;
  const int jbase = mem * JPB;

  unsigned short* hb = hbuf + g * (2 * ROWS * H_);
  int* cnt = cntg + g * 512;

  const int row = tid >> 3;  // 0..63
  const int seg = tid & 7;   // 0..7 (also local j)
  const int wv = tid >> 6;   // 0..7
  const int lane = tid & 63;

  // per-lane LN params (cols lane*4..+3)
  float4 lnw4 = *reinterpret_cast<const float4*>(ln_w + lane * 4);
  float4 lnb4 = *reinterpret_cast<const float4*>(ln_b + lane * 4);

  // ---- prologue: resident W slice [32 x 512] = [i|f|g|o rows for our 8 cols] ----
  {
    int n = tid >> 4, s16 = tid & 15;
    int g4 = n >> 3, jl = n & 7;
    int grow = g4 * 256 + jbase + jl;
    const float* src = (s16 < 8) ? (W_ih + grow * 256 + s16 * 32)
                                 : (W_hh + grow * 256 + (s16 - 8) * 32);
    unsigned short* dst = Wl + n * LDK + s16 * 32;
#pragma unroll
    for (int k = 0; k < 32; k += 4) {
      float4 v = *reinterpret_cast<const float4*>(src + k);
      ushort4 p;
      p.x = f2bf(v.x); p.y = f2bf(v.y); p.z = f2bf(v.z); p.w = f2bf(v.w);
      *reinterpret_cast<ushort4*>(dst + k) = p;
    }
  }
  if (tid < 32) {
    int grow = (tid >> 3) * 256 + jbase + (tid & 7);
    biasl[tid] = b_ih[grow] + b_hh[grow];
  }
  {  // publish h_{-1} = hx (rows 2*mem, 2*mem+1) into buffer 1
    int r = tid >> 8, cc = tid & 255;
    int lr = 2 * mem + r;
    hb[(ROWS + lr) * H_ + cc] = f2bf(hx[(rowbase + lr) * H_ + cc]);
  }
  float creg = cx[(rowbase + row) * H_ + jbase + seg];
  __syncthreads();
  if (tid == 0) {
    __threadfence();
    __hip_atomic_fetch_add(&cnt[0], 1, __ATOMIC_RELEASE, __HIP_MEMORY_SCOPE_AGENT);
  }

  auto do_ln = [&](int tp, const unsigned short* hbase) {
    if (wv < 2) {
      int lr = 2 * mem + wv;
      int gr = rowbase + lr;
      const unsigned short* hp = hbase + lr * H_ + lane * 4;
      float h0 = bf2f(hp[0]), h1 = bf2f(hp[1]), h2 = bf2f(hp[2]), h3 = bf2f(hp[3]);
      float s = h0 + h1 + h2 + h3;
      float q = h0 * h0 + h1 * h1 + h2 * h2 + h3 * h3;
#pragma unroll
      for (int m = 1; m < 64; m <<= 1) {
        s += __shfl_xor(s, m);
        q += __shfl_xor(q, m);
      }
      float mu = s * (1.0f / 256.0f);
      float var = q * (1.0f / 256.0f) - mu * mu;
      float rs = rsqrtf(var + 1e-5f);
      const float* xp = x + ((size_t)gr * T_ + tp) * I_ + lane * 4;
      float4 xv = *reinterpret_cast<const float4*>(xp);
      float4 o4;
      o4.x = (h0 - mu) * rs * lnw4.x + lnb4.x + xv.x;
      o4.y = (h1 - mu) * rs * lnw4.y + lnb4.y + xv.y;
      o4.z = (h2 - mu) * rs * lnw4.z + lnb4.z + xv.z;
      o4.w = (h3 - mu) * rs * lnw4.w + lnb4.w + xv.w;
      *reinterpret_cast<float4*>(out + ((size_t)gr * T_ + tp) * H_ + lane * 4) = o4;
    }
  };

  // ---- main loop over time ----
  for (int t = 0; t < T_; ++t) {
    const unsigned short* hbr = hb + ((t + 1) & 1) * (ROWS * H_);  // h_{t-1}
    unsigned short* hbw = hb + (t & 1) * (ROWS * H_);              // h_t

    // (A) stage x_t into In[:,0:256] (no dependency on h -> before the wait)
    {
      const float* xs = x + ((size_t)(rowbase + row) * T_ + t) * I_ + seg * 32;
      unsigned short* dst = In + row * LDK + seg * 32;
#pragma unroll
      for (int k = 0; k < 32; k += 4) {
        float4 v = *reinterpret_cast<const float4*>(xs + k);
        ushort4 p;
        p.x = f2bf(v.x); p.y = f2bf(v.y); p.z = f2bf(v.z); p.w = f2bf(v.w);
        *reinterpret_cast<ushort4*>(dst + k) = p;
      }
    }
    float rmask;
    {
      int ii = is_init[(rowbase + row) * T_ + t];
      rmask = ii ? 0.0f : 1.0f;
      if (seg == 0) rml[row] = rmask;
    }

    // (B) wait until all 32 blocks published h_{t-1}
    if (tid == 0) {
      while (__hip_atomic_load(&cnt[t], __ATOMIC_ACQUIRE, __HIP_MEMORY_SCOPE_AGENT) < BPG)
        __builtin_amdgcn_s_sleep(1);
    }
    __syncthreads();

    // (C) stage (reset-scaled) h_{t-1} into In[:,256:512]; LN(h_{t-1}) -> out[:,t-1]
    {
      float rm = rml[row];
      const uint4* src = reinterpret_cast<const uint4*>(hbr + row * H_ + seg * 32);
      uint4* dst = reinterpret_cast<uint4*>(In + row * LDK + 256 + seg * 32);
      uint4 z = make_uint4(0, 0, 0, 0);
#pragma unroll
      for (int q2 = 0; q2 < 4; ++q2) {
        uint4 v = src[q2];
        dst[q2] = (rm == 0.0f) ? z : v;
      }
    }
    if (t > 0) do_ln(t - 1, hbr);
    __syncthreads();

    // (D) GEMM: gates[64 rows x 32 gate-rows] = In[64x512] * Wl[32x512]^T
    {
      int mt = wv >> 1, nt = wv & 1;
      const unsigned short* ab = In + (mt * 16 + (lane & 15)) * LDK + ((lane >> 4) * 8);
      const unsigned short* bb = Wl + (nt * 16 + (lane & 15)) * LDK + ((lane >> 4) * 8);
      f32x4 acc0 = {0.f, 0.f, 0.f, 0.f}, acc1 = {0.f, 0.f, 0.f, 0.f};
#pragma unroll
      for (int kk = 0; kk < 512; kk += 64) {
        bfrag8 a0 = *reinterpret_cast<const bfrag8*>(ab + kk);
        bfrag8 b0 = *reinterpret_cast<const bfrag8*>(bb + kk);
        acc0 = __builtin_amdgcn_mfma_f32_16x16x32_bf16(a0, b0, acc0, 0, 0, 0);
        bfrag8 a1 = *reinterpret_cast<const bfrag8*>(ab + kk + 32);
        bfrag8 b1 = *reinterpret_cast<const bfrag8*>(bb + kk + 32);
        acc1 = __builtin_amdgcn_mfma_f32_16x16x32_bf16(a1, b1, acc1, 0, 0, 0);
      }
      f32x4 acc = acc0 + acc1;
#pragma unroll
      for (int r = 0; r < 4; ++r)
        gat[(mt * 16 + (lane >> 4) * 4 + r) * GLD + nt * 16 + (lane & 15)] = acc[r];
    }
    __syncthreads();

    // (F) pointwise cell update; publish h_t slice
    {
      float pi = gat[row * GLD + 0 + seg] + biasl[0 + seg];
      float pf = gat[row * GLD + 8 + seg] + biasl[8 + seg];
      float pg = gat[row * GLD + 16 + seg] + biasl[16 + seg];
      float po = gat[row * GLD + 24 + seg] + biasl[24 + seg];
      float ig = sigm(pi), fg = sigm(pf), gg = tanh_f(pg), og = sigm(po);
      float cp = creg * rmask;
      creg = fg * cp + ig * gg;
      float hn = og * tanh_f(creg);
      hbw[row * H_ + jbase + seg] = f2bf(hn);
    }
    __syncthreads();
    if (tid == 0) {
      __threadfence();
      __hip_atomic_fetch_add(&cnt[t + 1], 1, __ATOMIC_RELEASE, __HIP_MEMORY_SCOPE_AGENT);
    }
  }

  // ---- epilogue ----
  if (tid == 0) {
    while (__hip_atomic_load(&cnt[T_], __ATOMIC_ACQUIRE, __HIP_MEMORY_SCOPE_AGENT) < BPG)
      __builtin_amdgcn_s_sleep(1);
  }
  __syncthreads();
  const unsigned short* hT = hb + ROWS * H_;  // h_{255} lives in buffer 1
  do_ln(T_ - 1, hT);
  cts[(size_t)(rowbase + row) * H_ + jbase + seg] = creg;
  __syncthreads();
  if (tid == 0) {
    __threadfence();
    __hip_atomic_fetch_add(&cnt[T_ + 1], 1, __ATOMIC_RELEASE, __HIP_MEMORY_SCOPE_AGENT);
    while (__hip_atomic_load(&cnt[T_ + 1], __ATOMIC_ACQUIRE, __HIP_MEMORY_SCOPE_AGENT) < BPG)
      __builtin_amdgcn_s_sleep(1);
  }
  __syncthreads();
  {  // broadcast hT, cT over the T axis (pure coalesced writes)
    int r = tid >> 8;
    int lr = 2 * mem + r;
    int gr = rowbase + lr;
    int c4 = (tid & 63) * 4;
    int tph = (tid >> 6) & 3;
    float4 hv;
    hv.x = bf2f(hT[lr * H_ + c4 + 0]);
    hv.y = bf2f(hT[lr * H_ + c4 + 1]);
    hv.z = bf2f(hT[lr * H_ + c4 + 2]);
    hv.w = bf2f(hT[lr * H_ + c4 + 3]);
    float4 cv = *reinterpret_cast<const float4*>(cts + (size_t)gr * H_ + c4);
    float* o1 = out + (size_t)B_ * T_ * H_ + (size_t)gr * T_ * H_;
    float* o2 = o1 + (size_t)B_ * T_ * H_;
    for (int tt = tph; tt < T_; tt += 4) {
      *reinterpret_cast<float4*>(o1 + tt * H_ + c4) = hv;
      *reinterpret_cast<float4*>(o2 + tt * H_ + c4) = cv;
    }
  }
}

extern "C" void kernel_launch(void* const* d_in, const int* in_sizes, int n_in,
                              void* d_out, int out_size, void* d_ws, size_t ws_size,
                              hipStream_t stream) {
  (void)in_sizes; (void)n_in; (void)out_size; (void)ws_size;
  const float* x = (const float*)d_in[0];
  const int* is_init = (const int*)d_in[1];
  const float* hx = (const float*)d_in[2];
  const float* cx = (const float*)d_in[3];
  const float* W_ih = (const float*)d_in[4];
  const float* W_hh = (const float*)d_in[5];
  const float* b_ih = (const float*)d_in[6];
  const float* b_hh = (const float*)d_in[7];
  const float* ln_w = (const float*)d_in[8];
  const float* ln_b = (const float*)d_in[9];
  float* out = (float*)d_out;

  char* ws = (char*)d_ws;
  unsigned short* hbuf = (unsigned short*)ws;       // 8 groups * 2 * 64 * 256 bf16 = 512 KB
  float* cts = (float*)(ws + (512 << 10));          // 512 * 256 f32 = 512 KB
  int* cnt = (int*)(ws + (1 << 20));                // 8 * 512 ints = 16 KB

  hipMemsetAsync(cnt, 0, GROUPS * 512 * sizeof(int), stream);
  lstm_fused<<<dim3(GROUPS * BPG), dim3(NTHR), 0, stream>>>(
      x, is_init, hx, cx, W_ih, W_hh, b_ih, b_hh, ln_w, ln_b, out, hbuf, cts, cnt);
}

// Round 2
// 1641.183 us; speedup vs baseline: 3.2072x; 3.2072x over previous
//
#include <hip/hip_runtime.h>
#include <hip/hip_bf16.h>

typedef __attribute__((ext_vector_type(8))) short bfrag8;
typedef __attribute__((ext_vector_type(4))) float f32x4;

#define DEV static __device__ __forceinline__

constexpr int B_ = 512, T_ = 256, I_ = 256, H_ = 256;
constexpr int GROUPS = 8, BPG = 32, ROWS = 64, JPB = 8;
constexpr int NTHR = 512;
constexpr int LDK = 520;   // padded LDS row stride (bf16 elems) for K=512 tiles
constexpr int GLD = 33;    // gates LDS row stride (f32)
constexpr int DEPTH = 4;   // h ring depth (allows LN to run after arrival)

DEV unsigned short f2bf(float f) {
  __hip_bfloat16 h = __float2bfloat16(f);
  return *reinterpret_cast<unsigned short*>(&h);
}
DEV float bf2f(unsigned short u) {
  __hip_bfloat16 h;
  *reinterpret_cast<unsigned short*>(&h) = u;
  return __bfloat162float(h);
}
DEV float sigm(float x) { return 1.0f / (1.0f + __expf(-x)); }
DEV float tanh_f(float x) {
  float e = __expf(-2.0f * fabsf(x));
  float t = (1.0f - e) / (1.0f + e);
  return copysignf(t, x);
}

// ---- device-coherent (LLC) access helpers: no cache-maintenance ops ----
DEV void ld_sys_64B(const void* p, uint4& a, uint4& b, uint4& c, uint4& d) {
  asm volatile(
      "global_load_dwordx4 %0, %4, off sc0 sc1\n\t"
      "global_load_dwordx4 %1, %4, off offset:16 sc0 sc1\n\t"
      "global_load_dwordx4 %2, %4, off offset:32 sc0 sc1\n\t"
      "global_load_dwordx4 %3, %4, off offset:48 sc0 sc1\n\t"
      "s_waitcnt vmcnt(0)"
      : "=&v"(a), "=&v"(b), "=&v"(c), "=&v"(d)
      : "v"(p)
      : "memory");
}
DEV uint2 ld_sys_8B(const void* p) {
  uint2 r;
  asm volatile("global_load_dwordx2 %0, %1, off sc0 sc1\n\ts_waitcnt vmcnt(0)"
               : "=&v"(r) : "v"(p) : "memory");
  return r;
}
DEV void st_sys_u16(unsigned short* p, unsigned short v) {
  asm volatile("global_store_short %0, %1, off sc0 sc1" :: "v"(p), "v"(v) : "memory");
}
DEV void st_sys_u32(unsigned int* p, unsigned int v) {
  asm volatile("global_store_dword %0, %1, off sc0 sc1" :: "v"(p), "v"(v) : "memory");
}
DEV void drain_vm() { asm volatile("s_waitcnt vmcnt(0)" ::: "memory"); }
DEV void arrive(int* p) {
  __hip_atomic_fetch_add(p, 1, __ATOMIC_RELAXED, __HIP_MEMORY_SCOPE_SYSTEM);
}
DEV int poll(const int* p) {
  return __hip_atomic_load(p, __ATOMIC_RELAXED, __HIP_MEMORY_SCOPE_SYSTEM);
}

__global__ __launch_bounds__(NTHR, 2) void lstm_fused(
    const float* __restrict__ x, const int* __restrict__ is_init,
    const float* __restrict__ hx, const float* __restrict__ cx,
    const float* __restrict__ W_ih, const float* __restrict__ W_hh,
    const float* __restrict__ b_ih, const float* __restrict__ b_hh,
    const float* __restrict__ ln_w, const float* __restrict__ ln_b,
    float* __restrict__ out,
    unsigned short* __restrict__ hbuf, float* __restrict__ cts,
    int* __restrict__ cntg) {
  __shared__ unsigned short Wl[32 * LDK];   // [gate-slice 32][K 512+pad] bf16
  __shared__ unsigned short In[64 * LDK];   // [rows 64][x(256)|h(256)+pad] bf16
  __shared__ float gat[64 * GLD];           // gate pre-activations
  __shared__ float biasl[32];
  __shared__ float rml[64];

  const int tid = threadIdx.x;
  const int g = blockIdx.x & 7;
  const int mem = blockIdx.x >> 3;   // member 0..31 within group
  const int rowbase = g * ROWS;
  const int jbase = mem * JPB;

  unsigned short* hb = hbuf + g * (DEPTH * ROWS * H_);
  int* cnt = cntg + g * 512;

  const int row = tid >> 3;  // 0..63
  const int seg = tid & 7;   // 0..7 (also local j)
  const int wv = tid >> 6;   // 0..7
  const int lane = tid & 63;

  float4 lnw4 = *reinterpret_cast<const float4*>(ln_w + lane * 4);
  float4 lnb4 = *reinterpret_cast<const float4*>(ln_b + lane * 4);

  // ---- prologue: resident W slice [32 x 512] ----
  {
    int n = tid >> 4, s16 = tid & 15;
    int g4 = n >> 3, jl = n & 7;
    int grow = g4 * 256 + jbase + jl;
    const float* src = (s16 < 8) ? (W_ih + grow * 256 + s16 * 32)
                                 : (W_hh + grow * 256 + (s16 - 8) * 32);
    unsigned short* dst = Wl + n * LDK + s16 * 32;
#pragma unroll
    for (int k = 0; k < 32; k += 4) {
      float4 v = *reinterpret_cast<const float4*>(src + k);
      ushort4 p;
      p.x = f2bf(v.x); p.y = f2bf(v.y); p.z = f2bf(v.z); p.w = f2bf(v.w);
      *reinterpret_cast<ushort4*>(dst + k) = p;
    }
  }
  if (tid < 32) {
    int grow = (tid >> 3) * 256 + jbase + (tid & 7);
    biasl[tid] = b_ih[grow] + b_hh[grow];
  }
  {  // publish h_{-1} = hx into ring slot 3 (device-coherent stores)
    int r = tid >> 8, cc = tid & 255;
    int lr = 2 * mem + r;
    st_sys_u16(hb + (DEPTH - 1) * ROWS * H_ + lr * H_ + cc,
               f2bf(hx[(rowbase + lr) * H_ + cc]));
  }
  float creg = cx[(rowbase + row) * H_ + jbase + seg];
  drain_vm();
  __syncthreads();
  if (tid == 0) arrive(&cnt[0]);

  auto do_ln = [&](int tp, const unsigned short* hbase) {
    if (wv < 2) {
      int lr = 2 * mem + wv;
      int gr = rowbase + lr;
      uint2 hv = ld_sys_8B(hbase + lr * H_ + lane * 4);
      float h0 = bf2f((unsigned short)(hv.x & 0xffff));
      float h1 = bf2f((unsigned short)(hv.x >> 16));
      float h2 = bf2f((unsigned short)(hv.y & 0xffff));
      float h3 = bf2f((unsigned short)(hv.y >> 16));
      float s = h0 + h1 + h2 + h3;
      float q = h0 * h0 + h1 * h1 + h2 * h2 + h3 * h3;
#pragma unroll
      for (int m = 1; m < 64; m <<= 1) {
        s += __shfl_xor(s, m);
        q += __shfl_xor(q, m);
      }
      float mu = s * (1.0f / 256.0f);
      float var = q * (1.0f / 256.0f) - mu * mu;
      float rs = rsqrtf(var + 1e-5f);
      const float* xp = x + ((size_t)gr * T_ + tp) * I_ + lane * 4;
      float4 xv = *reinterpret_cast<const float4*>(xp);
      float4 o4;
      o4.x = (h0 - mu) * rs * lnw4.x + lnb4.x + xv.x;
      o4.y = (h1 - mu) * rs * lnw4.y + lnb4.y + xv.y;
      o4.z = (h2 - mu) * rs * lnw4.z + lnb4.z + xv.z;
      o4.w = (h3 - mu) * rs * lnw4.w + lnb4.w + xv.w;
      *reinterpret_cast<float4*>(out + ((size_t)gr * T_ + tp) * H_ + lane * 4) = o4;
    }
  };

  // ---- main loop over time ----
  for (int t = 0; t < T_; ++t) {
    const unsigned short* hbr = hb + ((t + DEPTH - 1) & (DEPTH - 1)) * (ROWS * H_);
    unsigned short* hbw = hb + (t & (DEPTH - 1)) * (ROWS * H_);

    // (A) stage x_t into In[:,0:256] (independent of h -> before the wait)
    {
      const float* xs = x + ((size_t)(rowbase + row) * T_ + t) * I_ + seg * 32;
      unsigned short* dst = In + row * LDK + seg * 32;
#pragma unroll
      for (int k = 0; k < 32; k += 4) {
        float4 v = *reinterpret_cast<const float4*>(xs + k);
        ushort4 p;
        p.x = f2bf(v.x); p.y = f2bf(v.y); p.z = f2bf(v.z); p.w = f2bf(v.w);
        *reinterpret_cast<ushort4*>(dst + k) = p;
      }
    }
    float rmask;
    {
      int ii = is_init[(rowbase + row) * T_ + t];
      rmask = ii ? 0.0f : 1.0f;
      if (seg == 0) rml[row] = rmask;
    }

    // (B) wait until all 32 blocks published h_{t-1}
    if (tid == 0) {
      while (poll(&cnt[t]) < BPG) __builtin_amdgcn_s_sleep(1);
    }
    __syncthreads();

    // (C) stage (reset-scaled) h_{t-1} into In[:,256:512] — one batched LLC RTT
    {
      float rm = rml[row];
      uint4 a, b, c, d;
      ld_sys_64B(hbr + row * H_ + seg * 32, a, b, c, d);
      uint4 z = make_uint4(0, 0, 0, 0);
      if (rm == 0.0f) { a = z; b = z; c = z; d = z; }
      uint4* dst = reinterpret_cast<uint4*>(In + row * LDK + 256 + seg * 32);
      dst[0] = a; dst[1] = b; dst[2] = c; dst[3] = d;
    }
    __syncthreads();

    // (D) GEMM: gates[64 x 32] = In[64x512] * Wl[32x512]^T
    {
      int mt = wv >> 1, nt = wv & 1;
      const unsigned short* ab = In + (mt * 16 + (lane & 15)) * LDK + ((lane >> 4) * 8);
      const unsigned short* bb = Wl + (nt * 16 + (lane & 15)) * LDK + ((lane >> 4) * 8);
      f32x4 acc0 = {0.f, 0.f, 0.f, 0.f}, acc1 = {0.f, 0.f, 0.f, 0.f};
#pragma unroll
      for (int kk = 0; kk < 512; kk += 64) {
        bfrag8 a0 = *reinterpret_cast<const bfrag8*>(ab + kk);
        bfrag8 b0 = *reinterpret_cast<const bfrag8*>(bb + kk);
        acc0 = __builtin_amdgcn_mfma_f32_16x16x32_bf16(a0, b0, acc0, 0, 0, 0);
        bfrag8 a1 = *reinterpret_cast<const bfrag8*>(ab + kk + 32);
        bfrag8 b1 = *reinterpret_cast<const bfrag8*>(bb + kk + 32);
        acc1 = __builtin_amdgcn_mfma_f32_16x16x32_bf16(a1, b1, acc1, 0, 0, 0);
      }
      f32x4 acc = acc0 + acc1;
#pragma unroll
      for (int r = 0; r < 4; ++r)
        gat[(mt * 16 + (lane >> 4) * 4 + r) * GLD + nt * 16 + (lane & 15)] = acc[r];
    }
    __syncthreads();

    // (F) pointwise cell update; publish h_t (device-coherent stores)
    {
      float pi = gat[row * GLD + 0 + seg] + biasl[0 + seg];
      float pf = gat[row * GLD + 8 + seg] + biasl[8 + seg];
      float pg = gat[row * GLD + 16 + seg] + biasl[16 + seg];
      float po = gat[row * GLD + 24 + seg] + biasl[24 + seg];
      float ig = sigm(pi), fg = sigm(pf), gg = tanh_f(pg), og = sigm(po);
      float cp = creg * rmask;
      creg = fg * cp + ig * gg;
      float hn = og * tanh_f(creg);
      st_sys_u16(hbw + row * H_ + jbase + seg, f2bf(hn));
    }
    drain_vm();
    __syncthreads();
    if (tid == 0) arrive(&cnt[t + 1]);

    // (G) off-critical-path: LN(h_{t-1}) + x skip -> out[:,t-1]
    //     (ring slot (t-1)&3 is not overwritten until step t+3)
    if (t > 0) do_ln(t - 1, hbr);
  }

  // ---- epilogue ----
  if (tid == 0) {
    while (poll(&cnt[T_]) < BPG) __builtin_amdgcn_s_sleep(1);
  }
  __syncthreads();
  const unsigned short* hT = hb + ((T_ - 1) & (DEPTH - 1)) * (ROWS * H_);
  do_ln(T_ - 1, hT);
  st_sys_u32(reinterpret_cast<unsigned int*>(cts + (size_t)(rowbase + row) * H_ + jbase + seg),
             __float_as_uint(creg));
  drain_vm();
  __syncthreads();
  if (tid == 0) {
    arrive(&cnt[T_ + 1]);
    while (poll(&cnt[T_ + 1]) < BPG) __builtin_amdgcn_s_sleep(1);
  }
  __syncthreads();
  {  // broadcast hT, cT over the T axis (coalesced cached writes)
    int r = tid >> 8;
    int lr = 2 * mem + r;
    int gr = rowbase + lr;
    int c4 = (tid & 63) * 4;
    int tph = (tid >> 6) & 3;
    uint2 hu = ld_sys_8B(hT + lr * H_ + c4);
    float4 hv;
    hv.x = bf2f((unsigned short)(hu.x & 0xffff));
    hv.y = bf2f((unsigned short)(hu.x >> 16));
    hv.z = bf2f((unsigned short)(hu.y & 0xffff));
    hv.w = bf2f((unsigned short)(hu.y >> 16));
    uint2 ca = ld_sys_8B(cts + (size_t)gr * H_ + c4);
    uint2 cb = ld_sys_8B(cts + (size_t)gr * H_ + c4 + 2);
    float4 cv;
    cv.x = __uint_as_float(ca.x); cv.y = __uint_as_float(ca.y);
    cv.z = __uint_as_float(cb.x); cv.w = __uint_as_float(cb.y);
    float* o1 = out + (size_t)B_ * T_ * H_ + (size_t)gr * T_ * H_;
    float* o2 = o1 + (size_t)B_ * T_ * H_;
    for (int tt = tph; tt < T_; tt += 4) {
      *reinterpret_cast<float4*>(o1 + tt * H_ + c4) = hv;
      *reinterpret_cast<float4*>(o2 + tt * H_ + c4) = cv;
    }
  }
}

extern "C" void kernel_launch(void* const* d_in, const int* in_sizes, int n_in,
                              void* d_out, int out_size, void* d_ws, size_t ws_size,
                              hipStream_t stream) {
  (void)in_sizes; (void)n_in; (void)out_size; (void)ws_size;
  const float* x = (const float*)d_in[0];
  const int* is_init = (const int*)d_in[1];
  const float* hx = (const float*)d_in[2];
  const float* cx = (const float*)d_in[3];
  const float* W_ih = (const float*)d_in[4];
  const float* W_hh = (const float*)d_in[5];
  const float* b_ih = (const float*)d_in[6];
  const float* b_hh = (const float*)d_in[7];
  const float* ln_w = (const float*)d_in[8];
  const float* ln_b = (const float*)d_in[9];
  float* out = (float*)d_out;

  char* ws = (char*)d_ws;
  unsigned short* hbuf = (unsigned short*)ws;       // 8 * 4 * 64 * 256 bf16 = 1 MB
  float* cts = (float*)(ws + (1 << 20));            // 512 * 256 f32 = 512 KB
  int* cnt = (int*)(ws + (1 << 20) + (512 << 10));  // 8 * 512 ints = 16 KB

  hipMemsetAsync(cnt, 0, GROUPS * 512 * sizeof(int), stream);
  lstm_fused<<<dim3(GROUPS * BPG), dim3(NTHR), 0, stream>>>(
      x, is_init, hx, cx, W_ih, W_hh, b_ih, b_hh, ln_w, ln_b, out, hbuf, cts, cnt);
}